// Round 6
// baseline (30.228 us; speedup 1.0000x reference)
//
#include <hip/hip_runtime.h>

// Problem constants
#define NSTEPS 255
#define TPTS   256          // time points incl t=0
#define NTRAJ  16384        // total trajectories
#define NBLK   256          // integration blocks, 64 trajectories each
#define ROWB   2040         // bytes per wvec row = 255 steps * 8 B (NOT 16-aligned!)

#define GAMMA_F 0.36f
#define OMEGA_F 5.0265f
#define DT_F    0.00390625f          // 2^-8
#define CW      0.0375f              // sqrt(GAMMA)*sqrt(DT) = 0.6/16 (exact)
#define GD      (GAMMA_F * DT_F)
#define OD      (OMEGA_F * DT_F)

// LDS tile: 64 rows x 128 B of w data, padded to 144 B row stride (bank rotate).
#define LROW  144
#define LBUF  (64 * LROW)   // 9216 B per buffer, x2 double buffer

typedef __fp16 half2v __attribute__((ext_vector_type(2)));
typedef float  f32x2  __attribute__((ext_vector_type(2)));

// pack two f32 -> fp16x2 in one instruction (v_cvt_pkrtz_f16_f32)
__device__ __forceinline__ unsigned pk2(float a, float b) {
  half2v h = __builtin_amdgcn_cvt_pkrtz(a, b);
  return __builtin_bit_cast(unsigned, h);
}

// ---- DPP wave64 sum: result lands in lane 63 (used only in reduce kernel) ----
template<int CTRL, int RM>
__device__ __forceinline__ float dpp_add(float v) {
  int sh = __builtin_amdgcn_update_dpp(0, __float_as_int(v), CTRL, RM, 0xf, true);
  return v + __int_as_float(sh);
}

__device__ __forceinline__ float wave_sum64(float v) {
  v = dpp_add<0x111, 0xf>(v);  // row_shr:1
  v = dpp_add<0x112, 0xf>(v);  // row_shr:2
  v = dpp_add<0x114, 0xf>(v);  // row_shr:4
  v = dpp_add<0x118, 0xf>(v);  // row_shr:8
  v = dpp_add<0x142, 0xa>(v);  // row_bcast:15
  v = dpp_add<0x143, 0xc>(v);  // row_bcast:31 -> lane63 = total
  return v;                    // valid in lane 63
}

// One Euler-Maruyama step, packed-f32 form. State: v = (x,y), z scalar.
#define STEP2(wx_, wy_) {                                                       \
  const float w0  = (wx_) * CW;                                                 \
  const f32x2 w1n = nCW2 * (wy_);              /* (-CW*wy, +CW*wy) */           \
  const f32x2 sw  = __builtin_shufflevector(v, v, 1, 0);   /* (y,x) */          \
  f32x2 t = __builtin_elementwise_fma(epack, sw, v);                            \
  t = __builtin_elementwise_fma(mGD2, v, t);                                    \
  const f32x2 p   = v * z;                                                      \
  const f32x2 mw0 = {-w0, -w0};                                                 \
  t = __builtin_elementwise_fma(p, mw0, t);                                     \
  t = __builtin_elementwise_fma(sw, w1n, t);                                    \
  t[1] = __builtin_fmaf(-OD, z, t[1]);                                          \
  const float a_ = __builtin_fmaf(OD, v[1], z);                                 \
  const float r_ = __builtin_fmaf(-(z * z), w0, w0);                            \
  v = t; z = a_ + r_;                                                           \
  *sp = make_uint2(pk2(v[0], v[1]), pk2(z, 0.0f));                              \
  sp += NTRAJ;                                                                  \
}

// Coalesced tile load, 8-byte granularity (ALWAYS 8-aligned: row*2040,
// (l&15)*8, and co=0 or 128c-8 are all 0 mod 8). Instr i covers rows
// 4i..4i+3 as 4 contiguous 128B segments.
#define GLOAD(co) {                                                             \
  _Pragma("unroll")                                                             \
  for (int i_ = 0; i_ < 16; ++i_)                                               \
    r2[i_] = *(const float2*)(wbp + (size_t)i_ * (4 * ROWB) + (co));            \
}

// 16x ds_write_b64: lane l writes LDS row (l>>4)+4i, bytes (l&15)*8..+8
#define LDSWRITE() {                                                            \
  _Pragma("unroll")                                                             \
  for (int i_ = 0; i_ < 16; ++i_)                                               \
    *(float2*)(smem + wl + i_ * (4 * LROW)) = r2[i_];                           \
}

// Compute NK steps of the chunk staged at LDS base rl (byte 8k = local step k)
#define CHUNK(NK) {                                                             \
  _Pragma("unroll")                                                             \
  for (int p_ = 0; p_ < 8; ++p_) {                                              \
    const float4 wv = *(const float4*)(smem + rl + p_ * 16);                    \
    STEP2(wv.x, wv.y);                                                          \
    if (2 * p_ + 1 < (NK)) STEP2(wv.z, wv.w);                                   \
  }                                                                             \
}

// grid = 256 blocks x 64 threads (1 wave); block g owns trajectories g*64..+63
// Chunk 0 = steps 0..14 (row bytes [0,128)); chunk c>=1 = 16 steps at row byte
// offset 128c-8 (steps 16c-1..16c+14), ending exactly at byte 2040 for c=15.
// Store: buf[t-1][n] = {pk(x,y), pk(z,0)}  (time-major).
__global__ __launch_bounds__(64) void sde_integrate(const float* __restrict__ inp,
                                                    const float* __restrict__ wvec,
                                                    uint2* __restrict__ buf) {
  __shared__ alignas(16) char smem[2 * LBUF];
  const int g = blockIdx.x, l = threadIdx.x;
  // trajectory n = g*64+l; eps = inputs[n % 32] = inputs[l & 31]
  const float eps = inp[l & 31];
  const f32x2 epack = {-eps * DT_F, eps * DT_F};
  const f32x2 mGD2  = {-GD, -GD};
  const f32x2 nCW2  = {-CW, CW};

  const char* wbp = (const char*)wvec
      + (size_t)(g * 64 + (l >> 4)) * ROWB + (l & 15) * 8;
  unsigned wl = (unsigned)((l >> 4) * LROW + (l & 15) * 8);  // LDS write base
  unsigned rl = (unsigned)(l * LROW);                        // LDS read base
  uint2* __restrict__ sp = buf + (g * 64 + l);

  f32x2 v = {0.0f, 0.0f};
  float z = 1.0f;
  float2 r2[16];

  GLOAD(0);           // chunk 0 -> regs
  LDSWRITE();         // -> buf 0
  __syncthreads();    // writes visible before reads (fence + lgkm drain)
  GLOAD(120);         // chunk 1 (row byte offset 128*1-8), covered by CHUNK
  CHUNK(15);          // steps 0..14 (t = 1..15)

  #pragma unroll 1
  for (int c = 1; c <= 15; ++c) {
    wl ^= LBUF; rl ^= LBUF;
    LDSWRITE();                        // chunk c (regs loaded last iter)
    __syncthreads();                   // lgkm drain; vmcnt already drained by
                                       // LDSWRITE's reg dep -> barrier is free
    if (c < 15) GLOAD(128 * c + 120);  // chunk c+1, issued AFTER barrier so it
                                       // overlaps with CHUNK's compute
    CHUNK(16);                         // 16 steps
  }
}

// One wave per (b, t) pair: sum 512 trajectories' fp16 states, emit 6 probs.
// 8192 waves = 2048 blocks x 256 threads -> full occupancy, coalesced reads.
__global__ __launch_bounds__(256) void sde_reduce(const uint2* __restrict__ buf,
                                                  float* __restrict__ out) {
  const int wid  = (blockIdx.x << 2) | (threadIdx.x >> 6);   // 0..8191 = b*256+t
  const int lane = threadIdx.x & 63;
  const int b = wid >> 8;
  const int t = wid & 255;
  float* o = out + (size_t)wid * 6;

  if (t == 0) {
    // exact initial state (0,0,1): probs = {0.5, 0.5, 0.5, 0.5, 1, 0}
    if (lane < 6) o[lane] = (lane == 4) ? 1.0f : ((lane == 5) ? 0.0f : 0.5f);
    return;
  }

  const uint2* base = buf + (size_t)(t - 1) * NTRAJ + (b << 9) + lane;
  float sx = 0.0f, sy = 0.0f, sz = 0.0f;
  #pragma unroll
  for (int k = 0; k < 8; ++k) {                 // sample n = b*512 + k*64 + lane
    const uint2 w = base[(size_t)k * 64];       // contiguous 512B per instr
    const half2v xy = __builtin_bit_cast(half2v, w.x);
    const half2v zp = __builtin_bit_cast(half2v, w.y);
    sx += (float)xy[0];
    sy += (float)xy[1];
    sz += (float)zp[0];
  }
  sx = wave_sum64(sx);
  sy = wave_sum64(sy);
  sz = wave_sum64(sz);

  if (lane == 63) {
    const float inv = 1.0f / 512.0f;
    const float mx = sx * inv, my = sy * inv, mz = sz * inv;
    o[0] = 0.5f * (1.0f + mx);
    o[1] = 0.5f * (1.0f - mx);
    o[2] = 0.5f * (1.0f + my);
    o[3] = 0.5f * (1.0f - my);
    o[4] = 0.5f * (1.0f + mz);
    o[5] = 0.5f * (1.0f - mz);
  }
}

extern "C" void kernel_launch(void* const* d_in, const int* in_sizes, int n_in,
                              void* d_out, int out_size, void* d_ws, size_t ws_size,
                              hipStream_t stream) {
  (void)in_sizes; (void)n_in; (void)out_size; (void)ws_size;
  const float* inp  = (const float*)d_in[0];   // [32]
  const float* wvec = (const float*)d_in[1];   // [16384][255][2]
  float* out  = (float*)d_out;                 // [32][256][6]
  uint2* buf  = (uint2*)d_ws;                  // 255*16384*8 B = 33.4 MB packed fp16 states

  sde_integrate<<<NBLK, 64, 0, stream>>>(inp, wvec, buf);
  sde_reduce<<<2048, 256, 0, stream>>>(buf, out);
}

// Round 7
// 23.007 us; speedup vs baseline: 1.3139x; 1.3139x over previous
//
#include <hip/hip_runtime.h>

// Problem constants
#define NSTEPS 255
#define TPTS   256          // time points incl t=0
#define NTRAJ  16384        // total trajectories
#define NBLK   256          // integration blocks, 64 trajectories each
#define CH     15           // steps per prefetch chunk; 17*15 = 255

#define GAMMA_F 0.36f
#define OMEGA_F 5.0265f
#define DT_F    0.00390625f          // 2^-8
#define CW      0.0375f              // sqrt(GAMMA)*sqrt(DT) = 0.6/16 (exact)
#define GD      (GAMMA_F * DT_F)
#define OD      (OMEGA_F * DT_F)

// LDS state history: [slot 0..254][lane 0..63] of fp16x4 {x,y,z,pad}.
// Row pitch 520 B (= 64*8 + 8 pad). Writes (per step, lanes consecutive 8B)
// and tail reads (lane-stride 520 B -> bank pairs 2l%32) are both at the
// structural b64 floor — no excess conflicts. Total 255*520 = 132600 B.
#define PITCH  520

typedef __fp16 half2v __attribute__((ext_vector_type(2)));
typedef float  f32x2  __attribute__((ext_vector_type(2)));

// pack two f32 -> fp16x2 in one instruction (v_cvt_pkrtz_f16_f32)
__device__ __forceinline__ unsigned pk2(float a, float b) {
  half2v h = __builtin_amdgcn_cvt_pkrtz(a, b);
  return __builtin_bit_cast(unsigned, h);
}

// One Euler-Maruyama step, packed-f32 form (R4-validated math).
// State: v = (x,y), z scalar. Writes fp16x4 state to LDS slot base sb + i*PITCH.
#define STEP2(w2, ii_) {                                                        \
  const float w0  = (w2).x * CW;                                                \
  const f32x2 w1n = nCW2 * (w2).y;             /* (-CW*wy, +CW*wy) */           \
  const f32x2 sw  = __builtin_shufflevector(v, v, 1, 0);   /* (y,x) */          \
  f32x2 t = __builtin_elementwise_fma(epack, sw, v);                            \
  t = __builtin_elementwise_fma(mGD2, v, t);                                    \
  const f32x2 p   = v * z;                                                      \
  const f32x2 mw0 = {-w0, -w0};                                                 \
  t = __builtin_elementwise_fma(p, mw0, t);                                     \
  t = __builtin_elementwise_fma(sw, w1n, t);                                    \
  t[1] = __builtin_fmaf(-OD, z, t[1]);                                          \
  const float a_ = __builtin_fmaf(OD, v[1], z);                                 \
  const float r_ = __builtin_fmaf(-(z * z), w0, w0);                            \
  v = t; z = a_ + r_;                                                           \
  *(uint2*)(sb + (ii_) * PITCH) = make_uint2(pk2(v[0], v[1]), pk2(z, 0.0f));    \
}

#define LOADC(BUF, CHUNK_) {                                                    \
  _Pragma("unroll")                                                             \
  for (int i_ = 0; i_ < CH; ++i_) BUF[i_] = wrow[(CHUNK_) * CH + i_];           \
}

#define PROC(BUF) {                                                             \
  _Pragma("unroll")                                                             \
  for (int i_ = 0; i_ < CH; ++i_) STEP2(BUF[i_], i_)                            \
  sb += CH * PITCH;                                                             \
}

// grid = 256 blocks x 64 threads (1 wave); block g owns trajectories g*64..+63.
// Loop: R4-validated direct w loads (distance-2 reg prefetch), per-step LDS
// state write. Tail: in-wave reduction over the 64 rows per slot -> partial
// sums partial[g][slot][3] (f32). t=0 handled in finalize.
__global__ __launch_bounds__(64) void sde_integrate(const float* __restrict__ inp,
                                                    const float* __restrict__ wvec,
                                                    float* __restrict__ partial) {
  __shared__ alignas(16) char smem[NSTEPS * PITCH];
  const int g = blockIdx.x, l = threadIdx.x;
  // trajectory n = g*64+l; eps = inputs[n % 32] = inputs[l & 31]
  const float eps = inp[l & 31];
  const f32x2 epack = {-eps * DT_F, eps * DT_F};
  const f32x2 mGD2  = {-GD, -GD};
  const f32x2 nCW2  = {-CW, CW};

  const float2* __restrict__ wrow =
      reinterpret_cast<const float2*>(wvec) + (size_t)(g * 64 + l) * NSTEPS;
  char* sb = smem + l * 8;             // slot 0, this lane's column

  f32x2 v = {0.0f, 0.0f};
  float z = 1.0f;

  float2 bufA[CH], bufB[CH], bufC[CH]; // static indexing only (regs)

  // prefetch distance 2: chunks c and c+1 in flight before computing c
  LOADC(bufA, 0);
  LOADC(bufB, 1);
  #pragma unroll 1
  for (int k = 0; k < 5; ++k) {        // chunks 3k..3k+2, loads 3k+2..3k+4
    LOADC(bufC, 3 * k + 2); PROC(bufA);
    LOADC(bufA, 3 * k + 3); PROC(bufB);
    LOADC(bufB, 3 * k + 4); PROC(bufC);
  }
  PROC(bufA);                          // chunk 15
  PROC(bufB);                          // chunk 16 (slots 240..254)

  __syncthreads();                     // single wave: cheap; orders LDS for tail

  // Tail: lane l reduces slots l, l+64, l+128, l+192 (skip >= 255).
  #pragma unroll
  for (int k = 0; k < 4; ++k) {
    const int s = l + 64 * k;
    if (s < NSTEPS) {
      const char* rb = smem + (size_t)s * PITCH;
      float fx = 0.0f, fy = 0.0f, fz = 0.0f;
      #pragma unroll
      for (int j = 0; j < 64; ++j) {
        const uint2 u = *(const uint2*)(rb + j * 8);
        const half2v xy = __builtin_bit_cast(half2v, u.x);
        const half2v zp = __builtin_bit_cast(half2v, u.y);
        fx += (float)xy[0];
        fy += (float)xy[1];
        fz += (float)zp[0];
      }
      float* p = partial + ((size_t)g * NSTEPS + s) * 3;
      p[0] = fx; p[1] = fy; p[2] = fz;
    }
  }
}

// one thread per (b, t): sum 8 block-partials, emit 6 probabilities
__global__ __launch_bounds__(256) void sde_finalize(const float* __restrict__ partial,
                                                    float* __restrict__ out) {
  const int idx = blockIdx.x * blockDim.x + threadIdx.x;   // b*256 + t, 8192 total
  const int b = idx >> 8;
  const int t = idx & 255;
  float* o = out + (size_t)idx * 6;

  if (t == 0) {
    // exact initial state (0,0,1): probs = {0.5, 0.5, 0.5, 0.5, 1, 0}
    o[0] = 0.5f; o[1] = 0.5f; o[2] = 0.5f; o[3] = 0.5f;
    o[4] = 1.0f; o[5] = 0.0f;
    return;
  }

  float sx = 0.0f, sy = 0.0f, sz = 0.0f;
  #pragma unroll
  for (int j = 0; j < 8; ++j) {
    const float* p = partial + ((size_t)(b * 8 + j) * NSTEPS + (t - 1)) * 3;
    sx += p[0]; sy += p[1]; sz += p[2];
  }
  const float inv = 1.0f / 512.0f;
  const float mx = sx * inv, my = sy * inv, mz = sz * inv;
  o[0] = 0.5f * (1.0f + mx);
  o[1] = 0.5f * (1.0f - mx);
  o[2] = 0.5f * (1.0f + my);
  o[3] = 0.5f * (1.0f - my);
  o[4] = 0.5f * (1.0f + mz);
  o[5] = 0.5f * (1.0f - mz);
}

extern "C" void kernel_launch(void* const* d_in, const int* in_sizes, int n_in,
                              void* d_out, int out_size, void* d_ws, size_t ws_size,
                              hipStream_t stream) {
  (void)in_sizes; (void)n_in; (void)out_size; (void)ws_size;
  const float* inp  = (const float*)d_in[0];   // [32]
  const float* wvec = (const float*)d_in[1];   // [16384][255][2]
  float* out     = (float*)d_out;              // [32][256][6]
  float* partial = (float*)d_ws;               // 256*255*3*4 = 783360 B

  sde_integrate<<<NBLK, 64, 0, stream>>>(inp, wvec, partial);
  sde_finalize<<<32, 256, 0, stream>>>(partial, out);
}